// Round 10
// baseline (435.525 us; speedup 1.0000x reference)
//
#include <hip/hip_runtime.h>
#include <stdint.h>
#include <stddef.h>

#define HIDDEN 2048
#define INTER  5632
#define TOKENS 4096   // B*S = 2*2048
#define BK     64     // f16 K-tile (down GEMM)  -> 128B rows, 88 iters
#define BKI    128    // i8 K-tile (gateup GEMM) -> 128B rows, 16 iters

typedef __attribute__((ext_vector_type(8))) _Float16 f16x8;
typedef __attribute__((ext_vector_type(4))) _Float16 f16x4;
typedef __attribute__((ext_vector_type(4))) float    f32x4;
typedef __attribute__((ext_vector_type(4))) int      i32x4;

// 128B-row LDS swizzle, period-8 row rotation: global segment q of row r lives
// at slot r*8 + ((q + r) & 7).  With the 16x16 fragment read pattern
// (q = ks*4 + lane>>4, row = base + lane&15) this measures ZERO
// SQ_LDS_BANK_CONFLICT (R7/R9).  Do NOT pair with 32x32 reads (R8 regression).
__device__ __forceinline__ int swz8(int row, int q) {
    return row * 8 + ((q + row) & 7);
}

// ---------------------------------------------------------------------------
// fused prepass: blocks [0,TOKENS) quantize x per-token to i8;
// blocks [TOKENS, TOKENS+2048) grid-stride convert weights
// (gate/up -> i8 exact; down -> f16 with down_s FOLDED IN)
// ---------------------------------------------------------------------------
__global__ __launch_bounds__(256)
void prepass(const float* __restrict__ x,
             const float4* __restrict__ gw, const float4* __restrict__ uw,
             const float4* __restrict__ dw, const float* __restrict__ dsc,
             int8_t* __restrict__ xq, float* __restrict__ xs,
             int* __restrict__ go, int* __restrict__ uo,
             f16x4* __restrict__ dno) {
    const int tid = threadIdx.x;
    if (blockIdx.x < TOKENS) {
        const int t = blockIdx.x;
        const float4* row = (const float4*)(x + (size_t)t * HIDDEN);
        float4 v0 = row[tid * 2];
        float4 v1 = row[tid * 2 + 1];
        float m = fmaxf(fmaxf(fabsf(v0.x), fabsf(v0.y)), fmaxf(fabsf(v0.z), fabsf(v0.w)));
        m = fmaxf(m, fmaxf(fmaxf(fabsf(v1.x), fabsf(v1.y)), fmaxf(fabsf(v1.z), fabsf(v1.w))));
        #pragma unroll
        for (int off = 32; off; off >>= 1)
            m = fmaxf(m, __shfl_xor(m, off, 64));
        __shared__ float wmax[4];
        if ((tid & 63) == 0) wmax[tid >> 6] = m;
        __syncthreads();
        m = fmaxf(fmaxf(wmax[0], wmax[1]), fmaxf(wmax[2], wmax[3]));
        m = fmaxf(m, 1e-20f);
        if (tid == 0) xs[t] = m * (1.0f / 127.0f);
        const float inv = 127.0f / m;
        float vals[8] = {v0.x, v0.y, v0.z, v0.w, v1.x, v1.y, v1.z, v1.w};
        int b[8];
        #pragma unroll
        for (int i = 0; i < 8; ++i) b[i] = (int)rintf(vals[i] * inv);
        int lo = (b[0] & 255) | ((b[1] & 255) << 8) | ((b[2] & 255) << 16) | (b[3] << 24);
        int hi = (b[4] & 255) | ((b[5] & 255) << 8) | ((b[6] & 255) << 16) | (b[7] << 24);
        ((int2*)(xq + (size_t)t * HIDDEN))[tid] = make_int2(lo, hi);
        return;
    }
    const int NW4 = INTER * HIDDEN / 4;
    int i = (blockIdx.x - TOKENS) * blockDim.x + tid;
    const int stride = 2048 * blockDim.x;
    for (; i < 3 * NW4; i += stride) {
        if (i < 2 * NW4) {
            const bool is_g = i < NW4;
            const int j = is_g ? i : i - NW4;
            float4 f = is_g ? gw[j] : uw[j];
            int p = ((int)(signed char)(int)f.x & 255)
                  | (((int)(signed char)(int)f.y & 255) << 8)
                  | (((int)(signed char)(int)f.z & 255) << 16)
                  | (((int)(signed char)(int)f.w) << 24);
            if (is_g) go[j] = p; else uo[j] = p;
        } else {
            const int j = i - 2 * NW4;
            float4 f = dw[j];
            const float s = dsc[(j * 4) / INTER];   // per-output-row scale
            f16x4 o;
            o.x = (_Float16)(f.x * s); o.y = (_Float16)(f.y * s);
            o.z = (_Float16)(f.z * s); o.w = (_Float16)(f.w * s);
            dno[j] = o;
        }
    }
}

// ---------------------------------------------------------------------------
// GEMM1 fused (i8): H = silu(G*xs*gs) * (U*xs*us)  (fp16 out)
// 128x128 tile, BKI=128 (16 K-iters), mfma_i32_16x16x64_i8, zero-conflict LDS.
// launch_bounds(256,3): 3 blocks/CU (LDS 3x48KB=144 <= 160KB, VGPR 104 -> fits)
// to add a third block's waves hiding the per-iter barrier drain (m114 model).
// ---------------------------------------------------------------------------
__global__ __launch_bounds__(256, 3)
void gemm_gateup(const int8_t* __restrict__ Xq,
                 const int8_t* __restrict__ Wg,
                 const int8_t* __restrict__ Wu,
                 const float* __restrict__ xs,
                 const float* __restrict__ gs,
                 const float* __restrict__ us,
                 _Float16* __restrict__ Hm) {
    __shared__ int8_t As [128 * BKI];
    __shared__ int8_t Bgs[128 * BKI];
    __shared__ int8_t Bus[128 * BKI];

    const int pid   = blockIdx.x;          // 0..1407
    const int local = pid % (16 * 44);
    const int bm    = ((pid / (16 * 44)) * 16 + (local & 15)) * 128;
    const int bn    = (local >> 4) * 128;

    const int tid  = threadIdx.x;
    const int lane = tid & 63;
    const int wave = tid >> 6;
    const int wm   = (wave >> 1) * 64;
    const int wn   = (wave & 1) * 64;
    const int l15  = lane & 15;
    const int lq   = lane >> 4;

    // staging: 1024 16B-slots/tile, 256 threads x 4. slot f -> row f>>3,
    // fetches permuted global segment ((f&7) - row) & 7.
    int rowA[4], sgA[4];
    #pragma unroll
    for (int j = 0; j < 4; ++j) {
        const int f = tid + 256 * j;
        rowA[j] = f >> 3;
        sgA[j]  = (((f & 7) - rowA[j]) & 7) * 16;
    }

    i32x4 accg[4][4] = {};
    i32x4 accu[4][4] = {};

    for (int k0 = 0; k0 < HIDDEN; k0 += BKI) {
        #pragma unroll
        for (int j = 0; j < 4; ++j) {
            const int f = tid + 256 * j;
            const int8_t* pX = Xq + (size_t)(bm + rowA[j]) * HIDDEN + k0 + sgA[j];
            const int8_t* pG = Wg + (size_t)(bn + rowA[j]) * HIDDEN + k0 + sgA[j];
            const int8_t* pU = Wu + (size_t)(bn + rowA[j]) * HIDDEN + k0 + sgA[j];
            __builtin_amdgcn_global_load_lds(
                (__attribute__((address_space(1))) void*)pX,
                (__attribute__((address_space(3))) void*)&As[f * 16], 16, 0, 0);
            __builtin_amdgcn_global_load_lds(
                (__attribute__((address_space(1))) void*)pG,
                (__attribute__((address_space(3))) void*)&Bgs[f * 16], 16, 0, 0);
            __builtin_amdgcn_global_load_lds(
                (__attribute__((address_space(1))) void*)pU,
                (__attribute__((address_space(3))) void*)&Bus[f * 16], 16, 0, 0);
        }
        __syncthreads();

        #pragma unroll
        for (int ks = 0; ks < 2; ++ks) {
            const int q = ks * 4 + lq;     // segment for this MFMA k-step
            i32x4 a[4];
            #pragma unroll
            for (int im = 0; im < 4; ++im)
                a[im] = *(const i32x4*)&As[swz8(wm + im * 16 + l15, q) * 16];
            #pragma unroll
            for (int jn = 0; jn < 4; ++jn) {
                i32x4 bg = *(const i32x4*)&Bgs[swz8(wn + jn * 16 + l15, q) * 16];
                i32x4 bu = *(const i32x4*)&Bus[swz8(wn + jn * 16 + l15, q) * 16];
                #pragma unroll
                for (int im = 0; im < 4; ++im) {
                    accg[im][jn] = __builtin_amdgcn_mfma_i32_16x16x64_i8(a[im], bg, accg[im][jn], 0, 0, 0);
                    accu[im][jn] = __builtin_amdgcn_mfma_i32_16x16x64_i8(a[im], bu, accu[im][jn], 0, 0, 0);
                }
            }
        }
        __syncthreads();
    }

    #pragma unroll
    for (int jn = 0; jn < 4; ++jn) {
        const int col = bn + wn + jn * 16 + l15;
        const float sg = gs[col];
        const float su = us[col];
        #pragma unroll
        for (int im = 0; im < 4; ++im) {
            const int rbase = bm + wm + im * 16 + lq * 4;
            #pragma unroll
            for (int r = 0; r < 4; ++r) {
                const int row = rbase + r;
                const float st = xs[row];
                float g = (float)accg[im][jn][r] * st * sg;
                float u = (float)accu[im][jn][r] * st * su;
                float h = (g / (1.0f + __expf(-g))) * u;
                Hm[(size_t)row * INTER + col] = (_Float16)h;
            }
        }
    }
}

// ---------------------------------------------------------------------------
// GEMM2 (fp16): out = H @ Wdh^T  (Wdh pre-scaled by down_s; fp32 out)
// 128x128 tile, BK=64 (88 K-iters), mfma_f32_16x16x32_f16, zero-conflict LDS.
// Grid = 512 = 2 blocks/CU exactly; R4 proved more residency doesn't help.
// ---------------------------------------------------------------------------
__global__ __launch_bounds__(256, 2)
void gemm_down(const _Float16* __restrict__ Hm,
               const _Float16* __restrict__ Wd,
               float* __restrict__ out) {
    __shared__ _Float16 As[128 * BK];
    __shared__ _Float16 Bs[128 * BK];

    const int pid = blockIdx.x;            // 0..511
    const int loc = pid & 255;
    const int bm  = ((pid >> 8) * 16 + (loc & 15)) * 128;
    const int bn  = (loc >> 4) * 128;

    const int tid  = threadIdx.x;
    const int lane = tid & 63;
    const int wave = tid >> 6;
    const int wm   = (wave >> 1) * 64;
    const int wn   = (wave & 1) * 64;
    const int l15  = lane & 15;
    const int lq   = lane >> 4;

    int rowA[4], sgA[4];
    #pragma unroll
    for (int j = 0; j < 4; ++j) {
        const int f = tid + 256 * j;
        rowA[j] = f >> 3;
        sgA[j]  = (((f & 7) - rowA[j]) & 7) * 8;   // f16 elements
    }

    f32x4 acc[4][4] = {};

    for (int k0 = 0; k0 < INTER; k0 += BK) {
        #pragma unroll
        for (int j = 0; j < 4; ++j) {
            const int f = tid + 256 * j;
            const _Float16* pA = Hm + (size_t)(bm + rowA[j]) * INTER + k0 + sgA[j];
            const _Float16* pB = Wd + (size_t)(bn + rowA[j]) * INTER + k0 + sgA[j];
            __builtin_amdgcn_global_load_lds(
                (__attribute__((address_space(1))) void*)pA,
                (__attribute__((address_space(3))) void*)&As[f * 8], 16, 0, 0);
            __builtin_amdgcn_global_load_lds(
                (__attribute__((address_space(1))) void*)pB,
                (__attribute__((address_space(3))) void*)&Bs[f * 8], 16, 0, 0);
        }
        __syncthreads();

        #pragma unroll
        for (int ks = 0; ks < 2; ++ks) {
            const int q = ks * 4 + lq;
            f16x8 a[4];
            #pragma unroll
            for (int im = 0; im < 4; ++im)
                a[im] = *(const f16x8*)&As[swz8(wm + im * 16 + l15, q) * 8];
            #pragma unroll
            for (int jn = 0; jn < 4; ++jn) {
                f16x8 b = *(const f16x8*)&Bs[swz8(wn + jn * 16 + l15, q) * 8];
                #pragma unroll
                for (int im = 0; im < 4; ++im)
                    acc[im][jn] = __builtin_amdgcn_mfma_f32_16x16x32_f16(a[im], b, acc[im][jn], 0, 0, 0);
            }
        }
        __syncthreads();
    }

    #pragma unroll
    for (int jn = 0; jn < 4; ++jn) {
        const int col = bn + wn + jn * 16 + l15;
        #pragma unroll
        for (int im = 0; im < 4; ++im) {
            const int rbase = bm + wm + im * 16 + lq * 4;
            #pragma unroll
            for (int r = 0; r < 4; ++r)
                out[(size_t)(rbase + r) * HIDDEN + col] = acc[im][jn][r];
        }
    }
}

// ---------------------------------------------------------------------------
// launch
// ---------------------------------------------------------------------------
extern "C" void kernel_launch(void* const* d_in, const int* in_sizes, int n_in,
                              void* d_out, int out_size, void* d_ws, size_t ws_size,
                              hipStream_t stream) {
    const float* x   = (const float*)d_in[0];
    const float* gw  = (const float*)d_in[1];
    const float* uw  = (const float*)d_in[2];
    const float* dw  = (const float*)d_in[3];
    const float* gsc = (const float*)d_in[4];
    const float* usc = (const float*)d_in[5];
    const float* dsc = (const float*)d_in[6];
    float* out = (float*)d_out;

    // workspace layout:
    //   Xq  i8  @          0 :  8,388,608
    //   Wg8 i8  @  8,388,608 : 11,534,336
    //   Wu8 i8  @ 19,922,944 : 11,534,336
    //   Wdh f16 @ 31,457,280 : 23,068,672
    //   Hm  f16 @ 54,525,952 : 46,137,344
    //   xs  f32 @100,663,296 :     16,384
    char* ws = (char*)d_ws;
    int8_t*   Xq  = (int8_t*)(ws);
    int8_t*   Wg8 = (int8_t*)(ws + 8388608ull);
    int8_t*   Wu8 = (int8_t*)(ws + 19922944ull);
    _Float16* Wdh = (_Float16*)(ws + 31457280ull);
    _Float16* Hm  = (_Float16*)(ws + 54525952ull);
    float*    xs  = (float*)(ws + 100663296ull);

    prepass<<<TOKENS + 2048, 256, 0, stream>>>(
        x, (const float4*)gw, (const float4*)uw, (const float4*)dw, dsc,
        Xq, xs, (int*)Wg8, (int*)Wu8, (f16x4*)Wdh);

    gemm_gateup<<<(INTER / 128) * (TOKENS / 128), 256, 0, stream>>>(
        Xq, Wg8, Wu8, xs, gsc, usc, Hm);
    gemm_down<<<(HIDDEN / 128) * (TOKENS / 128), 256, 0, stream>>>(
        Hm, Wdh, out);
}

// Round 11
// 380.972 us; speedup vs baseline: 1.1432x; 1.1432x over previous
//
#include <hip/hip_runtime.h>
#include <stdint.h>
#include <stddef.h>

#define HIDDEN 2048
#define INTER  5632
#define TOKENS 4096   // B*S = 2*2048
#define BK     64     // f16 K-tile (down GEMM)  -> 128B rows, 88 iters
#define BKI    128    // i8 K-tile (gateup GEMM) -> 128B rows, 16 iters

typedef __attribute__((ext_vector_type(8))) _Float16 f16x8;
typedef __attribute__((ext_vector_type(4))) _Float16 f16x4;
typedef __attribute__((ext_vector_type(4))) float    f32x4;
typedef __attribute__((ext_vector_type(4))) int      i32x4;

// 128B-row LDS swizzle, period-8 row rotation: global segment q of row r lives
// at slot r*8 + ((q + r) & 7).  With the 16x16 fragment read pattern
// (q = ks*4 + lane>>4, row = base + lane&15) this measures ZERO
// SQ_LDS_BANK_CONFLICT (R7/R9).  Do NOT pair with 32x32 reads (R8 regression).
__device__ __forceinline__ int swz8(int row, int q) {
    return row * 8 + ((q + row) & 7);
}

// ---------------------------------------------------------------------------
// fused prepass: blocks [0,TOKENS) quantize x per-token to i8;
// blocks [TOKENS, TOKENS+2048) grid-stride convert weights
// (gate/up -> i8 exact; down -> f16 with down_s FOLDED IN)
// ---------------------------------------------------------------------------
__global__ __launch_bounds__(256)
void prepass(const float* __restrict__ x,
             const float4* __restrict__ gw, const float4* __restrict__ uw,
             const float4* __restrict__ dw, const float* __restrict__ dsc,
             int8_t* __restrict__ xq, float* __restrict__ xs,
             int* __restrict__ go, int* __restrict__ uo,
             f16x4* __restrict__ dno) {
    const int tid = threadIdx.x;
    if (blockIdx.x < TOKENS) {
        const int t = blockIdx.x;
        const float4* row = (const float4*)(x + (size_t)t * HIDDEN);
        float4 v0 = row[tid * 2];
        float4 v1 = row[tid * 2 + 1];
        float m = fmaxf(fmaxf(fabsf(v0.x), fabsf(v0.y)), fmaxf(fabsf(v0.z), fabsf(v0.w)));
        m = fmaxf(m, fmaxf(fmaxf(fabsf(v1.x), fabsf(v1.y)), fmaxf(fabsf(v1.z), fabsf(v1.w))));
        #pragma unroll
        for (int off = 32; off; off >>= 1)
            m = fmaxf(m, __shfl_xor(m, off, 64));
        __shared__ float wmax[4];
        if ((tid & 63) == 0) wmax[tid >> 6] = m;
        __syncthreads();
        m = fmaxf(fmaxf(wmax[0], wmax[1]), fmaxf(wmax[2], wmax[3]));
        m = fmaxf(m, 1e-20f);
        if (tid == 0) xs[t] = m * (1.0f / 127.0f);
        const float inv = 127.0f / m;
        float vals[8] = {v0.x, v0.y, v0.z, v0.w, v1.x, v1.y, v1.z, v1.w};
        int b[8];
        #pragma unroll
        for (int i = 0; i < 8; ++i) b[i] = (int)rintf(vals[i] * inv);
        int lo = (b[0] & 255) | ((b[1] & 255) << 8) | ((b[2] & 255) << 16) | (b[3] << 24);
        int hi = (b[4] & 255) | ((b[5] & 255) << 8) | ((b[6] & 255) << 16) | (b[7] << 24);
        ((int2*)(xq + (size_t)t * HIDDEN))[tid] = make_int2(lo, hi);
        return;
    }
    const int NW4 = INTER * HIDDEN / 4;
    int i = (blockIdx.x - TOKENS) * blockDim.x + tid;
    const int stride = 2048 * blockDim.x;
    for (; i < 3 * NW4; i += stride) {
        if (i < 2 * NW4) {
            const bool is_g = i < NW4;
            const int j = is_g ? i : i - NW4;
            float4 f = is_g ? gw[j] : uw[j];
            int p = ((int)(signed char)(int)f.x & 255)
                  | (((int)(signed char)(int)f.y & 255) << 8)
                  | (((int)(signed char)(int)f.z & 255) << 16)
                  | (((int)(signed char)(int)f.w) << 24);
            if (is_g) go[j] = p; else uo[j] = p;
        } else {
            const int j = i - 2 * NW4;
            float4 f = dw[j];
            const float s = dsc[(j * 4) / INTER];   // per-output-row scale
            f16x4 o;
            o.x = (_Float16)(f.x * s); o.y = (_Float16)(f.y * s);
            o.z = (_Float16)(f.z * s); o.w = (_Float16)(f.w * s);
            dno[j] = o;
        }
    }
}

// ---------------------------------------------------------------------------
// GEMM1 fused (i8): H = silu(G*xs*gs) * (U*xs*us)  (fp16 out)
// 128x128 tile, BKI=128 (16 K-iters), mfma_i32_16x16x64_i8, zero-conflict LDS.
// launch_bounds(256,2): the 128-reg accumulator tile needs ~104 VGPRs;
// forcing 3 blocks/CU (R10) capped VGPR at 84 -> scratch spills
// (WRITE_SIZE 49->205 MB), dur 105->170 us. Occupancy is NOT binding here.
// ---------------------------------------------------------------------------
__global__ __launch_bounds__(256, 2)
void gemm_gateup(const int8_t* __restrict__ Xq,
                 const int8_t* __restrict__ Wg,
                 const int8_t* __restrict__ Wu,
                 const float* __restrict__ xs,
                 const float* __restrict__ gs,
                 const float* __restrict__ us,
                 _Float16* __restrict__ Hm) {
    __shared__ int8_t As [128 * BKI];
    __shared__ int8_t Bgs[128 * BKI];
    __shared__ int8_t Bus[128 * BKI];

    const int pid   = blockIdx.x;          // 0..1407
    const int local = pid % (16 * 44);
    const int bm    = ((pid / (16 * 44)) * 16 + (local & 15)) * 128;
    const int bn    = (local >> 4) * 128;

    const int tid  = threadIdx.x;
    const int lane = tid & 63;
    const int wave = tid >> 6;
    const int wm   = (wave >> 1) * 64;
    const int wn   = (wave & 1) * 64;
    const int l15  = lane & 15;
    const int lq   = lane >> 4;

    // staging: 1024 16B-slots/tile, 256 threads x 4. slot f -> row f>>3,
    // fetches permuted global segment ((f&7) - row) & 7.
    int rowA[4], sgA[4];
    #pragma unroll
    for (int j = 0; j < 4; ++j) {
        const int f = tid + 256 * j;
        rowA[j] = f >> 3;
        sgA[j]  = (((f & 7) - rowA[j]) & 7) * 16;
    }

    i32x4 accg[4][4] = {};
    i32x4 accu[4][4] = {};

    for (int k0 = 0; k0 < HIDDEN; k0 += BKI) {
        #pragma unroll
        for (int j = 0; j < 4; ++j) {
            const int f = tid + 256 * j;
            const int8_t* pX = Xq + (size_t)(bm + rowA[j]) * HIDDEN + k0 + sgA[j];
            const int8_t* pG = Wg + (size_t)(bn + rowA[j]) * HIDDEN + k0 + sgA[j];
            const int8_t* pU = Wu + (size_t)(bn + rowA[j]) * HIDDEN + k0 + sgA[j];
            __builtin_amdgcn_global_load_lds(
                (__attribute__((address_space(1))) void*)pX,
                (__attribute__((address_space(3))) void*)&As[f * 16], 16, 0, 0);
            __builtin_amdgcn_global_load_lds(
                (__attribute__((address_space(1))) void*)pG,
                (__attribute__((address_space(3))) void*)&Bgs[f * 16], 16, 0, 0);
            __builtin_amdgcn_global_load_lds(
                (__attribute__((address_space(1))) void*)pU,
                (__attribute__((address_space(3))) void*)&Bus[f * 16], 16, 0, 0);
        }
        __syncthreads();

        #pragma unroll
        for (int ks = 0; ks < 2; ++ks) {
            const int q = ks * 4 + lq;     // segment for this MFMA k-step
            i32x4 a[4];
            #pragma unroll
            for (int im = 0; im < 4; ++im)
                a[im] = *(const i32x4*)&As[swz8(wm + im * 16 + l15, q) * 16];
            #pragma unroll
            for (int jn = 0; jn < 4; ++jn) {
                i32x4 bg = *(const i32x4*)&Bgs[swz8(wn + jn * 16 + l15, q) * 16];
                i32x4 bu = *(const i32x4*)&Bus[swz8(wn + jn * 16 + l15, q) * 16];
                #pragma unroll
                for (int im = 0; im < 4; ++im) {
                    accg[im][jn] = __builtin_amdgcn_mfma_i32_16x16x64_i8(a[im], bg, accg[im][jn], 0, 0, 0);
                    accu[im][jn] = __builtin_amdgcn_mfma_i32_16x16x64_i8(a[im], bu, accu[im][jn], 0, 0, 0);
                }
            }
        }
        __syncthreads();
    }

    #pragma unroll
    for (int jn = 0; jn < 4; ++jn) {
        const int col = bn + wn + jn * 16 + l15;
        const float sg = gs[col];
        const float su = us[col];
        #pragma unroll
        for (int im = 0; im < 4; ++im) {
            const int rbase = bm + wm + im * 16 + lq * 4;
            #pragma unroll
            for (int r = 0; r < 4; ++r) {
                const int row = rbase + r;
                const float st = xs[row];
                float g = (float)accg[im][jn][r] * st * sg;
                float u = (float)accu[im][jn][r] * st * su;
                float h = (g / (1.0f + __expf(-g))) * u;
                Hm[(size_t)row * INTER + col] = (_Float16)h;
            }
        }
    }
}

// ---------------------------------------------------------------------------
// GEMM2 (fp16): out = H @ Wdh^T  (Wdh pre-scaled by down_s; fp32 out)
// 128x128 tile, BK=64 (88 K-iters), mfma_f32_16x16x32_f16, zero-conflict LDS.
// ---------------------------------------------------------------------------
__global__ __launch_bounds__(256, 2)
void gemm_down(const _Float16* __restrict__ Hm,
               const _Float16* __restrict__ Wd,
               float* __restrict__ out) {
    __shared__ _Float16 As[128 * BK];
    __shared__ _Float16 Bs[128 * BK];

    const int pid = blockIdx.x;            // 0..511
    const int loc = pid & 255;
    const int bm  = ((pid >> 8) * 16 + (loc & 15)) * 128;
    const int bn  = (loc >> 4) * 128;

    const int tid  = threadIdx.x;
    const int lane = tid & 63;
    const int wave = tid >> 6;
    const int wm   = (wave >> 1) * 64;
    const int wn   = (wave & 1) * 64;
    const int l15  = lane & 15;
    const int lq   = lane >> 4;

    int rowA[4], sgA[4];
    #pragma unroll
    for (int j = 0; j < 4; ++j) {
        const int f = tid + 256 * j;
        rowA[j] = f >> 3;
        sgA[j]  = (((f & 7) - rowA[j]) & 7) * 8;   // f16 elements
    }

    f32x4 acc[4][4] = {};

    for (int k0 = 0; k0 < INTER; k0 += BK) {
        #pragma unroll
        for (int j = 0; j < 4; ++j) {
            const int f = tid + 256 * j;
            const _Float16* pA = Hm + (size_t)(bm + rowA[j]) * INTER + k0 + sgA[j];
            const _Float16* pB = Wd + (size_t)(bn + rowA[j]) * INTER + k0 + sgA[j];
            __builtin_amdgcn_global_load_lds(
                (__attribute__((address_space(1))) void*)pA,
                (__attribute__((address_space(3))) void*)&As[f * 8], 16, 0, 0);
            __builtin_amdgcn_global_load_lds(
                (__attribute__((address_space(1))) void*)pB,
                (__attribute__((address_space(3))) void*)&Bs[f * 8], 16, 0, 0);
        }
        __syncthreads();

        #pragma unroll
        for (int ks = 0; ks < 2; ++ks) {
            const int q = ks * 4 + lq;
            f16x8 a[4];
            #pragma unroll
            for (int im = 0; im < 4; ++im)
                a[im] = *(const f16x8*)&As[swz8(wm + im * 16 + l15, q) * 8];
            #pragma unroll
            for (int jn = 0; jn < 4; ++jn) {
                f16x8 b = *(const f16x8*)&Bs[swz8(wn + jn * 16 + l15, q) * 8];
                #pragma unroll
                for (int im = 0; im < 4; ++im)
                    acc[im][jn] = __builtin_amdgcn_mfma_f32_16x16x32_f16(a[im], b, acc[im][jn], 0, 0, 0);
            }
        }
        __syncthreads();
    }

    #pragma unroll
    for (int jn = 0; jn < 4; ++jn) {
        const int col = bn + wn + jn * 16 + l15;
        #pragma unroll
        for (int im = 0; im < 4; ++im) {
            const int rbase = bm + wm + im * 16 + lq * 4;
            #pragma unroll
            for (int r = 0; r < 4; ++r)
                out[(size_t)(rbase + r) * HIDDEN + col] = acc[im][jn][r];
        }
    }
}

// ---------------------------------------------------------------------------
// launch
// ---------------------------------------------------------------------------
extern "C" void kernel_launch(void* const* d_in, const int* in_sizes, int n_in,
                              void* d_out, int out_size, void* d_ws, size_t ws_size,
                              hipStream_t stream) {
    const float* x   = (const float*)d_in[0];
    const float* gw  = (const float*)d_in[1];
    const float* uw  = (const float*)d_in[2];
    const float* dw  = (const float*)d_in[3];
    const float* gsc = (const float*)d_in[4];
    const float* usc = (const float*)d_in[5];
    const float* dsc = (const float*)d_in[6];
    float* out = (float*)d_out;

    // workspace layout:
    //   Xq  i8  @          0 :  8,388,608
    //   Wg8 i8  @  8,388,608 : 11,534,336
    //   Wu8 i8  @ 19,922,944 : 11,534,336
    //   Wdh f16 @ 31,457,280 : 23,068,672
    //   Hm  f16 @ 54,525,952 : 46,137,344
    //   xs  f32 @100,663,296 :     16,384
    char* ws = (char*)d_ws;
    int8_t*   Xq  = (int8_t*)(ws);
    int8_t*   Wg8 = (int8_t*)(ws + 8388608ull);
    int8_t*   Wu8 = (int8_t*)(ws + 19922944ull);
    _Float16* Wdh = (_Float16*)(ws + 31457280ull);
    _Float16* Hm  = (_Float16*)(ws + 54525952ull);
    float*    xs  = (float*)(ws + 100663296ull);

    prepass<<<TOKENS + 2048, 256, 0, stream>>>(
        x, (const float4*)gw, (const float4*)uw, (const float4*)dw, dsc,
        Xq, xs, (int*)Wg8, (int*)Wu8, (f16x4*)Wdh);

    gemm_gateup<<<(INTER / 128) * (TOKENS / 128), 256, 0, stream>>>(
        Xq, Wg8, Wu8, xs, gsc, usc, Hm);
    gemm_down<<<(HIDDEN / 128) * (TOKENS / 128), 256, 0, stream>>>(
        Hm, Wdh, out);
}